// Round 5
// baseline (428.333 us; speedup 1.0000x reference)
//
#include <hip/hip_runtime.h>
#include <stdint.h>

// Problem constants (fixed by setup_inputs; all tensors f32)
#define B_ROWS 4096
#define D_IN   784
#define H_DIM  800
#define D_OUT  10
#define T_SIM  32
#define N_ELEM (B_ROWS * D_IN)   // 3211264 = 12544 * 256

// ---------------------------------------------------------------------------
// Bit-exact JAX threefry2x32 (key = PRNGKey(42) = {0, 42})
// ---------------------------------------------------------------------------
__device__ __forceinline__ void threefry2x32(uint32_t k0, uint32_t k1,
                                             uint32_t& x0, uint32_t& x1) {
  uint32_t ks0 = k0, ks1 = k1, ks2 = k0 ^ k1 ^ 0x1BD11BDAu;
  x0 += ks0; x1 += ks1;
#define TF_RND(r) { x0 += x1; x1 = (x1 << (r)) | (x1 >> (32 - (r))); x1 ^= x0; }
  TF_RND(13) TF_RND(15) TF_RND(26) TF_RND(6)
  x0 += ks1; x1 += ks2 + 1u;
  TF_RND(17) TF_RND(29) TF_RND(16) TF_RND(24)
  x0 += ks2; x1 += ks0 + 2u;
  TF_RND(13) TF_RND(15) TF_RND(26) TF_RND(6)
  x0 += ks0; x1 += ks1 + 3u;
  TF_RND(17) TF_RND(29) TF_RND(16) TF_RND(24)
  x0 += ks1; x1 += ks2 + 4u;
  TF_RND(13) TF_RND(15) TF_RND(26) TF_RND(6)
  x0 += ks2; x1 += ks0 + 5u;
#undef TF_RND
}

// K0: x_fixed[i] = (u[i] < x[i]) ? 1 : 0 with u = jax.random.uniform(key(42)),
// jax_threefry_partitionable=True (modern default):
//   per-element counter (hi, lo) = (0, i); bits = out0 ^ out1
//   u = bitcast((bits >> 9) | 0x3F800000) - 1.0f    (exact f32 ops)
__global__ __launch_bounds__(256) void gen_xfixed(const float* __restrict__ x,
                                                  float* __restrict__ xf) {
  int i = blockIdx.x * blockDim.x + threadIdx.x;
  if (i >= N_ELEM) return;
  uint32_t c0 = 0u, c1 = (uint32_t)i;
  threefry2x32(0u, 42u, c0, c1);
  uint32_t bits = c0 ^ c1;
  float u = __uint_as_float((bits >> 9) | 0x3F800000u) - 1.0f;
  xf[i] = (u < x[i]) ? 1.0f : 0.0f;
}

// ---------------------------------------------------------------------------
// K1: cur1 = x_fixed @ W1^T + b1 in f32 (M=4096, N=800, K=784).
// Bit-exact vs np.matmul: per output element a SINGLE f32 accumulator over
// strictly ascending k (BLAS microkernel semantics). Since x_fixed ∈ {0,1},
// fma vs mul+add is immaterial: every step is round(acc + W1) or identity.
// ---------------------------------------------------------------------------
#define BM 64
#define BN 64
#define BK 16

__global__ __launch_bounds__(256) void gemm_cur1(const float* __restrict__ xf,
                                                 const float* __restrict__ W1,
                                                 const float* __restrict__ b1,
                                                 float* __restrict__ cur1) {
  __shared__ float As[BK][BM + 1];
  __shared__ float Bs[BK][BN + 1];
  const int m0 = blockIdx.y * BM;
  const int n0 = blockIdx.x * BN;
  const int t  = threadIdx.x;        // 0..255
  const int tx = t & 15, ty = t >> 4;
  float acc[4][4] = {};
  for (int kt = 0; kt < D_IN; kt += BK) {   // 784 = 49*16, ascending k
#pragma unroll
    for (int i = 0; i < 4; i++) {
      int e = t + 256 * i;
      int mm = e >> 4, kk = e & 15;
      As[kk][mm] = xf[(m0 + mm) * D_IN + kt + kk];
    }
#pragma unroll
    for (int i = 0; i < 4; i++) {
      int e = t + 256 * i;
      int nn = e >> 4, kk = e & 15;
      int h = n0 + nn;
      Bs[kk][nn] = (h < H_DIM) ? W1[h * D_IN + kt + kk] : 0.0f;
    }
    __syncthreads();
#pragma unroll
    for (int kk = 0; kk < BK; kk++) {       // strict ascending k, single acc
      float a[4], b[4];
#pragma unroll
      for (int i = 0; i < 4; i++) a[i] = As[kk][ty * 4 + i];
#pragma unroll
      for (int i = 0; i < 4; i++) b[i] = Bs[kk][tx * 4 + i];
#pragma unroll
      for (int mi = 0; mi < 4; mi++)
#pragma unroll
        for (int ni = 0; ni < 4; ni++)
          acc[mi][ni] = __builtin_fmaf(a[mi], b[ni], acc[mi][ni]);
    }
    __syncthreads();
  }
#pragma unroll
  for (int mi = 0; mi < 4; mi++) {
    int m = m0 + ty * 4 + mi;
#pragma unroll
    for (int ni = 0; ni < 4; ni++) {
      int h = n0 + tx * 4 + ni;
      if (h < H_DIM)
        cur1[m * H_DIM + h] = acc[mi][ni] + b1[h];   // f32 add, like ref
    }
  }
}

// ---------------------------------------------------------------------------
// K2: 32-step SNN scan in exact f32 reference order.
// Layer 1: hard reset (v = h1*(1-spk) = +0.0 on spike) + time-constant cur1
// => exactly periodic spikes even in f32; build 32-bit spike mask per neuron
// using the identical f32 add chain. Layer 2: cur2[t][o] = (ascending-h
// single-accumulator gated add chain) + b2 — bit-exact vs np.matmul with a
// {0,1} left operand. Then the f32 layer-2 IF scan and spike count.
// ---------------------------------------------------------------------------
__global__ __launch_bounds__(320) void snn_scan(const float* __restrict__ cur1,
                                                const float* __restrict__ W2,
                                                const float* __restrict__ b2,
                                                float* __restrict__ out) {
  __shared__ uint32_t mask[H_DIM];           // spike mask per layer-1 neuron
  __shared__ float    W2s[D_OUT][H_DIM + 1]; // +1 anti-conflict
  __shared__ float    c2s[T_SIM + 1][D_OUT]; // cur2 per (t,o)
  __shared__ float    b2f[D_OUT];
  const int tid = threadIdx.x;               // 0..319
  const int row = blockIdx.x;

  // Phase A: periods -> masks (f32 add chain identical to reference scan)
  for (int h = tid; h < H_DIM; h += 320) {
    float c = cur1[(size_t)row * H_DIM + h];
    float v = 0.0f;
    int p = 0;
#pragma unroll 1
    for (int m = 1; m <= T_SIM; m++) {
      float h1 = v + c;                      // f32 add, as reference
      if (h1 >= 1.0f) { p = m; break; }      // heaviside(h1 - 1) >= 0
      v = h1;
    }
    uint32_t mk = 0;
    if (p) for (int tt = p; tt <= T_SIM; tt += p) mk |= (1u << (tt - 1));
    mask[h] = mk;
  }
  // Phase B: W2, b2 to LDS
  for (int e = tid; e < D_OUT * H_DIM; e += 320)
    W2s[e / H_DIM][e % H_DIM] = W2[e];
  if (tid < D_OUT) b2f[tid] = b2[tid];
  __syncthreads();

  // Phase C: cur2[t][o] — ascending-h, single f32 accumulator, gated adds
  {
    const int tt = tid / D_OUT + 1;          // 1..32
    const int o  = tid % D_OUT;
    const uint32_t bit = 1u << (tt - 1);
    float s = 0.0f;
#pragma unroll 4
    for (int h = 0; h < H_DIM; h++) {
      float w = W2s[o][h];
      s += (mask[h] & bit) ? w : 0.0f;       // == fma(spk, w, s)
    }
    c2s[tt][o] = s + b2f[o];                 // f32 add of b2, like ref
  }
  __syncthreads();

  // Phase D: layer-2 IF scan + count (f32; counts <= 32 exact)
  if (tid < D_OUT) {
    const int o = tid;
    float v = 0.0f; int cnt = 0;
#pragma unroll
    for (int tt = 1; tt <= T_SIM; tt++) {
      float h2 = v + c2s[tt][o];             // f32 add
      bool spk = (h2 >= 1.0f);
      cnt += spk ? 1 : 0;
      v = spk ? 0.0f : h2;                   // h2*(1-spk): exact
    }
    out[(size_t)row * D_OUT + o] = (float)cnt;
  }
}

// ---------------------------------------------------------------------------
extern "C" void kernel_launch(void* const* d_in, const int* in_sizes, int n_in,
                              void* d_out, int out_size, void* d_ws, size_t ws_size,
                              hipStream_t stream) {
  const float* x  = (const float*)d_in[0];
  const float* W1 = (const float*)d_in[1];
  const float* b1 = (const float*)d_in[2];
  const float* W2 = (const float*)d_in[3];
  const float* b2 = (const float*)d_in[4];
  float* outp = (float*)d_out;

  float* xf   = (float*)d_ws;                      // N_ELEM f32 (12.85 MB)
  float* cur1 = xf + N_ELEM;                       // B*H  f32 (13.1 MB)

  gen_xfixed<<<N_ELEM / 256, 256, 0, stream>>>(x, xf);

  dim3 g1((H_DIM + BN - 1) / BN, B_ROWS / BM);     // 13 x 64
  gemm_cur1<<<g1, 256, 0, stream>>>(xf, W1, b1, cur1);

  snn_scan<<<B_ROWS, 320, 0, stream>>>(cur1, W2, b2, outp);
}